// Round 7
// baseline (344.041 us; speedup 1.0000x reference)
//
#include <hip/hip_runtime.h>
#include <hip/hip_bf16.h>
#include <stdint.h>

#define B_ROWS 16384
#define K_DIM  2048   // IN + H
#define H_DIM  1024
#define N_DIM  4096   // 4*H
#define KB     (K_DIM * 2)      // bytes per packed row (4096)
#define NT     (K_DIM / 64)     // 32 K-tiles of BK=64
#define BUFSZ  65536u           // one LDS buffer: A 32K + B 32K

using f32x4   = __attribute__((ext_vector_type(4))) float;
using f32x16  = __attribute__((ext_vector_type(16))) float;
using bf16x8  = __attribute__((ext_vector_type(8))) __bf16;

// RNE float -> bf16 (inputs are finite)
__device__ __forceinline__ unsigned short f2bf(float f) {
    union { float f; unsigned u; } v; v.f = f;
    unsigned r = v.u + 0x7fffu + ((v.u >> 16) & 1u);
    return (unsigned short)(r >> 16);
}

// async global->LDS, 16B/lane. LDS dest must be wave-uniform (HW adds lane*16).
__device__ __forceinline__ void gload16(const void* g, const void* l) {
    __builtin_amdgcn_global_load_lds(
        (const __attribute__((address_space(1))) void*)g,
        (__attribute__((address_space(3))) void*)l,
        16, 0, 0);
}

__device__ __forceinline__ float rcp1p(float e) {   // 1/(1+e)
    return __builtin_amdgcn_rcpf(1.f + e);
}

// ---------------- pack kernels (unchanged, verified) ----------------
__global__ void pack_a_kernel(const float* __restrict__ x, const float* __restrict__ h0,
                              unsigned short* __restrict__ A) {
    int tid = blockIdx.x * 256 + threadIdx.x;
    int64_t idx = (int64_t)tid * 4;
    int b = (int)(idx >> 11);
    int k = (int)(idx & 2047);
    const float* src = (k < 1024) ? (x + (int64_t)b * 1024 + k)
                                  : (h0 + (int64_t)b * 1024 + (k - 1024));
    float4 v = *(const float4*)src;
    ushort4 o;
    o.x = f2bf(v.x); o.y = f2bf(v.y); o.z = f2bf(v.z); o.w = f2bf(v.w);
    *(ushort4*)(A + idx) = o;
}

__global__ void pack_w_kernel(const float* __restrict__ wi, const float* __restrict__ wh,
                              const float* __restrict__ bi, const float* __restrict__ bh,
                              unsigned short* __restrict__ W, float* __restrict__ bias) {
    int tid = blockIdx.x * 256 + threadIdx.x;
    int64_t idx = (int64_t)tid * 4;
    int r = (int)(idx >> 11);
    int k = (int)(idx & 2047);
    int h = r >> 2, g = r & 3;
    const float* src = (k < 1024)
        ? (wi + (int64_t)g * 1048576 + (int64_t)h * 1024 + k)
        : (wh + (int64_t)g * 1048576 + (int64_t)h * 1024 + (k - 1024));
    float4 v = *(const float4*)src;
    ushort4 o;
    o.x = f2bf(v.x); o.y = f2bf(v.y); o.z = f2bf(v.z); o.w = f2bf(v.w);
    *(ushort4*)(W + idx) = o;
    if (k == 0) bias[r] = bi[g * 1024 + h] + bh[g * 1024 + h];
}

// ---- 256x256 GEMM, 32x32x16 MFMA, 2 phases/K-tile + fused LSTM epilogue ----
// LDS buffer (x2 @ 0/65536): A kk0 @0 (16K), A kk1 @16384, B kk0 @32768, B kk1 @49152.
// Byte layout + st_16x32 swizzle + linear-dest staging with inverse-swizzled source:
// IDENTICAL to verified r5/r6. Subtile byte = (row&15)*64 + (col ^ ((row&8)<<2)).
// 32x32x16 A-frag (row = l&31, k = (l>>5)*8+j within kstep ks): read as two 16-row
// subtiles: addr = chunk + (frag*2 + ((l>>4)&1))*1024 + (l&15)*64
//                + (l>>5)*16 + (((l&8)<<2) ^ ks*32).
// Phase = {12 ds_reads; 4 gload stages; BAR; lgkm0; 16 MFMA; vmcnt(4); BAR} x2/K-tile.
// vmcnt(4) covering: in-flight 8, drains the kk-half consumed one phase later (r5-proven).

#define SCHED0  __builtin_amdgcn_sched_barrier(0)
#define FENCE   asm volatile("" ::: "memory")
#define BAR     __builtin_amdgcn_s_barrier()

#define PH_PRE  do { FENCE; BAR; \
                     asm volatile("s_waitcnt lgkmcnt(0)" ::: "memory"); \
                     SCHED0; __builtin_amdgcn_s_setprio(1); } while (0)
#define PH_POST_V do { __builtin_amdgcn_s_setprio(0); SCHED0; \
                       asm volatile("s_waitcnt vmcnt(4)" ::: "memory"); \
                       SCHED0; FENCE; BAR; } while (0)

__global__ __launch_bounds__(512, 2) void lstm_gemm_fused(
    const unsigned short* __restrict__ A, const unsigned short* __restrict__ W,
    const float* __restrict__ bias, const float* __restrict__ c0,
    float* __restrict__ ht, float* __restrict__ ct)
{
    __shared__ char sm[131072];

    const int tid = threadIdx.x;
    const int l   = tid & 63;
    const int w   = tid >> 6;         // wave 0..7
    const int wm  = w >> 2;           // 0..1  (row half: 128 rows)
    const int wn  = w & 3;            // 0..3  (col quarter: 64 cols)

    // XCD-aware bijective swizzle (1024 blocks, %8==0)
    const int bid = blockIdx.x;
    const int nid = (bid & 7) * 128 + (bid >> 3);
    const int bm  = nid >> 4;         // 0..63 (M tiles)
    const int bn  = nid & 15;         // 0..15 (N tiles)

    f32x16 acc[4][2];
#pragma unroll
    for (int i = 0; i < 4; ++i)
#pragma unroll
        for (int j = 0; j < 2; ++j)
#pragma unroll
            for (int e = 0; e < 16; ++e) acc[i][j][e] = 0.f;

    // ---- staging source addressing (inverse-swizzled), pointer-bumped per tile ----
    const int srow = w * 16 + (l >> 2);                 // 0..127
    const int scb  = ((l & 3) << 4) ^ (l & 32);
    const char* Asrc = (const char*)A + (size_t)(bm * 256 + srow) * KB + scb;
    const char* Wsrc = (const char*)W + (size_t)(bn * 256 + srow) * KB + scb;
    const uint32_t wL = (uint32_t)w * 1024u;            // wave-uniform LDS dest part

#define STAGE_A(KK, BOFF) do { \
    gload16(Asrc + (KK) * 64,            sm + (BOFF) + (KK) * 16384u + wL); \
    gload16(Asrc + (KK) * 64 + 128 * KB, sm + (BOFF) + (KK) * 16384u + 8192u + wL); \
} while (0)
#define STAGE_B(KK, BOFF) do { \
    gload16(Wsrc + (KK) * 64,            sm + (BOFF) + 32768u + (KK) * 16384u + wL); \
    gload16(Wsrc + (KK) * 64 + 128 * KB, sm + (BOFF) + 32768u + (KK) * 16384u + 8192u + wL); \
} while (0)

    // ---- 32x32x16 fragment read addressing (swizzled, two 16-row subtiles) ----
    const uint32_t sub   = ((uint32_t)(l >> 4) & 1u) * 1024u;
    const uint32_t lofA  = (uint32_t)(l & 15) * 64u + ((uint32_t)(l >> 5)) * 16u;
    const uint32_t xr    = (uint32_t)((l & 8) << 2);        // 0 or 32
    const uint32_t lane0 = sub + lofA + xr;                 // ks=0 column
    const uint32_t lane1 = sub + lofA + (xr ^ 32u);         // ks=1 column
    const uint32_t ArdB  = (uint32_t)wm * 8192u;            // + chunk + mf*2048 + laneK
    const uint32_t BrdB  = 32768u + (uint32_t)wn * 4096u;   // + chunk + nf*2048 + laneK

    bf16x8 af[4][2], bf[2][2];

#define RD_PHASE(BOFF, KK) do { \
    const uint32_t cb_ = (BOFF) + (KK) * 16384u; \
    _Pragma("unroll") \
    for (int mf_ = 0; mf_ < 4; ++mf_) { \
        af[mf_][0] = *(const bf16x8*)(sm + cb_ + ArdB + mf_ * 2048u + lane0); \
        af[mf_][1] = *(const bf16x8*)(sm + cb_ + ArdB + mf_ * 2048u + lane1); \
    } \
    _Pragma("unroll") \
    for (int nf_ = 0; nf_ < 2; ++nf_) { \
        bf[nf_][0] = *(const bf16x8*)(sm + cb_ + BrdB + nf_ * 2048u + lane0); \
        bf[nf_][1] = *(const bf16x8*)(sm + cb_ + BrdB + nf_ * 2048u + lane1); \
    } \
} while (0)

#define MFMA16 do { \
    _Pragma("unroll") \
    for (int ks_ = 0; ks_ < 2; ++ks_) \
        _Pragma("unroll") \
        for (int mf_ = 0; mf_ < 4; ++mf_) \
            _Pragma("unroll") \
            for (int nf_ = 0; nf_ < 2; ++nf_) \
                acc[mf_][nf_] = __builtin_amdgcn_mfma_f32_32x32x16_bf16( \
                    af[mf_][ks_], bf[nf_][ks_], acc[mf_][nf_], 0, 0, 0); \
} while (0)

    // ---- prologue: stage tile 0 fully; wait its kk0 half; bump to tile 1 ----
    STAGE_A(0, 0u); STAGE_B(0, 0u);   // kk0 (4 loads)
    STAGE_A(1, 0u); STAGE_B(1, 0u);   // kk1 (4 loads)
    Asrc += 128; Wsrc += 128;
    asm volatile("s_waitcnt vmcnt(4)" ::: "memory");
    SCHED0; FENCE; BAR;

    // ---- main loop: 2 phases/tile ----
#define DO_TILE(CUR, NXT) do { \
    /* P0: kk0 */ \
    RD_PHASE(CUR, 0); \
    STAGE_A(0, NXT); STAGE_B(0, NXT); \
    PH_PRE; MFMA16; PH_POST_V; \
    /* P1: kk1 */ \
    RD_PHASE(CUR, 1); \
    STAGE_A(1, NXT); STAGE_B(1, NXT); \
    PH_PRE; MFMA16; PH_POST_V; \
    Asrc += 128; Wsrc += 128; \
} while (0)

#pragma unroll 1
    for (int tt = 0; tt < NT; tt += 2) {
        DO_TILE(0u, BUFSZ);
        DO_TILE(BUFSZ, 0u);
    }

    // ---- fused LSTM epilogue (32x32 C/D map: col=l&31, row=(reg&3)+8*(reg>>2)+4*(l>>5)) ----
    asm volatile("s_waitcnt vmcnt(0) lgkmcnt(0)" ::: "memory");
    FENCE; BAR;

    float* ep = (float*)(void*)sm + w * 2176;   // 32 rows x 68 floats per wave
    const int hbase = bn * 64 + wn * 16;
    const int rbase = bm * 256 + wm * 128;
    const int rl = (l >> 5) * 4;
    const int cl = l & 31;

#pragma unroll
    for (int mf = 0; mf < 4; ++mf) {
        // scatter acc[mf][*] (32 rows x 64 cols) to LDS, padded stride 68
#pragma unroll
        for (int nf = 0; nf < 2; ++nf)
#pragma unroll
            for (int g = 0; g < 4; ++g)
#pragma unroll
                for (int ri = 0; ri < 4; ++ri)
                    ep[(ri + g * 8 + rl) * 68 + nf * 32 + cl] = acc[mf][nf][g * 4 + ri];

        // gather: 512 cells = 32 rows x 16 h-quads; lane handles 8
#pragma unroll
        for (int it = 0; it < 8; ++it) {
            const int c   = it * 64 + l;
            const int row = c >> 4;
            const int hq  = c & 15;
            f32x4 z = *(const f32x4*)(ep + row * 68 + hq * 4);
            const int hg = hbase + hq;
            const float4 bz = ((const float4*)bias)[hg];
            const int brow = rbase + mf * 32 + row;

            float zf = z.x + bz.x;
            float zi = z.y + bz.y;
            float zo = z.z + bz.z;
            float zg = z.w + bz.w;

            float fg = rcp1p(__expf(-zf));                   // sigmoid
            float ig = rcp1p(__expf(-zi));
            float og = rcp1p(__expf(-zo));
            float gg = 2.f * rcp1p(__expf(-2.f * zg)) - 1.f; // tanh

            int64_t oi = (int64_t)brow * H_DIM + hg;
            float cc = fg * c0[oi] + ig * gg;
            float hh = og * (2.f * rcp1p(__expf(-2.f * cc)) - 1.f);
            ct[oi] = cc;
            ht[oi] = hh;
        }
    }
}

extern "C" void kernel_launch(void* const* d_in, const int* in_sizes, int n_in,
                              void* d_out, int out_size, void* d_ws, size_t ws_size,
                              hipStream_t stream) {
    const float* x  = (const float*)d_in[0];
    const float* h0 = (const float*)d_in[1];
    const float* c0 = (const float*)d_in[2];
    const float* wi = (const float*)d_in[3];
    const float* bi = (const float*)d_in[4];
    const float* wh = (const float*)d_in[5];
    const float* bh = (const float*)d_in[6];

    float* ht = (float*)d_out;
    float* ct = ht + (int64_t)B_ROWS * H_DIM;

    char* ws = (char*)d_ws;
    unsigned short* A  = (unsigned short*)ws;                       // 64 MiB
    unsigned short* Wp = (unsigned short*)(ws + (64u << 20));       // 16 MiB
    float*          bs = (float*)(ws + (80u << 20));                // 16 KiB

    pack_a_kernel<<<32768, 256, 0, stream>>>(x, h0, A);
    pack_w_kernel<<<8192, 256, 0, stream>>>(wi, wh, bi, bh, Wp, bs);

    lstm_gemm_fused<<<1024, 512, 0, stream>>>(A, Wp, bs, c0, ht, ct);
}

// Round 8
// 334.157 us; speedup vs baseline: 1.0296x; 1.0296x over previous
//
#include <hip/hip_runtime.h>
#include <hip/hip_bf16.h>
#include <stdint.h>

#define B_ROWS 16384
#define K_DIM  2048   // IN + H
#define H_DIM  1024
#define N_DIM  4096   // 4*H
#define KB     (K_DIM * 2)      // bytes per packed row (4096)
#define NT     (K_DIM / 64)     // 32 K-tiles of BK=64
#define BUF0   0u
#define BUF1   65536u           // LDS double buffer: A 32K + B 32K each

using f32x4   = __attribute__((ext_vector_type(4))) float;
using f32x16  = __attribute__((ext_vector_type(16))) float;
using bf16x8  = __attribute__((ext_vector_type(8))) __bf16;

// RNE float -> bf16 (inputs are finite)
__device__ __forceinline__ unsigned short f2bf(float f) {
    union { float f; unsigned u; } v; v.f = f;
    unsigned r = v.u + 0x7fffu + ((v.u >> 16) & 1u);
    return (unsigned short)(r >> 16);
}

// async global->LDS, 16B/lane. LDS dest must be wave-uniform (HW adds lane*16).
__device__ __forceinline__ void gload16(const void* g, const void* l) {
    __builtin_amdgcn_global_load_lds(
        (const __attribute__((address_space(1))) void*)g,
        (__attribute__((address_space(3))) void*)l,
        16, 0, 0);
}

__device__ __forceinline__ float rcp1p(float e) {   // 1/(1+e)
    return __builtin_amdgcn_rcpf(1.f + e);
}

// ---------------- pack kernels (unchanged, verified) ----------------
__global__ void pack_a_kernel(const float* __restrict__ x, const float* __restrict__ h0,
                              unsigned short* __restrict__ A) {
    int tid = blockIdx.x * 256 + threadIdx.x;
    int64_t idx = (int64_t)tid * 4;
    int b = (int)(idx >> 11);
    int k = (int)(idx & 2047);
    const float* src = (k < 1024) ? (x + (int64_t)b * 1024 + k)
                                  : (h0 + (int64_t)b * 1024 + (k - 1024));
    float4 v = *(const float4*)src;
    ushort4 o;
    o.x = f2bf(v.x); o.y = f2bf(v.y); o.z = f2bf(v.z); o.w = f2bf(v.w);
    *(ushort4*)(A + idx) = o;
}

__global__ void pack_w_kernel(const float* __restrict__ wi, const float* __restrict__ wh,
                              const float* __restrict__ bi, const float* __restrict__ bh,
                              unsigned short* __restrict__ W, float* __restrict__ bias) {
    int tid = blockIdx.x * 256 + threadIdx.x;
    int64_t idx = (int64_t)tid * 4;
    int r = (int)(idx >> 11);
    int k = (int)(idx & 2047);
    int h = r >> 2, g = r & 3;
    const float* src = (k < 1024)
        ? (wi + (int64_t)g * 1048576 + (int64_t)h * 1024 + k)
        : (wh + (int64_t)g * 1048576 + (int64_t)h * 1024 + (k - 1024));
    float4 v = *(const float4*)src;
    ushort4 o;
    o.x = f2bf(v.x); o.y = f2bf(v.y); o.z = f2bf(v.z); o.w = f2bf(v.w);
    *(ushort4*)(W + idx) = o;
    if (k == 0) bias[r] = bi[g * 1024 + h] + bh[g * 1024 + h];
}

// ---- 256x256 GEMM, 32x32x16 MFMA, read-ahead windows + fused LSTM epilogue ----
// LDS buffer (x2 @ 0/65536): A kk0 @0 (16K), A kk1 @16384, B kk0 @32768, B kk1 @49152.
// Swizzle (extends r2-verified st_16x32 with a row&16 term to kill the 32x32 2x slot
// aliasing seen in r7): physical col = logical ^ ((row&8)<<2) ^ ((row&16)?16:0).
// Staging: linear-dest gload_lds, inverse-swizzled source (row&16 = (w&1)<<4, uniform).
// Window = { vmcnt(4); BAR; fence; rd B(prev-win tile,kk); rd A(this tile,kk)->alt bank;
//            stage 4 gloads (tile+1, kk); setprio1; 16 MFMA (prev bank); setprio0 }
// No lgkmcnt(0)/sched_barrier: reads are compiler-visible loads -> progressive counted
// lgkmcnt; A-prefetch drains under the MFMA cluster (LDS pipe || MFMA pipe).
// RAW: reads sit after a BAR that all waves pass only post-vmcnt(4) (r4 discipline).
// WAR: stages target regions last read >=1 barrier earlier + DMA latency margin.

#define FENCE asm volatile("" ::: "memory")
#define BAR   __builtin_amdgcn_s_barrier()
#define VM4   asm volatile("s_waitcnt vmcnt(4)" ::: "memory")
#define SP1   __builtin_amdgcn_s_setprio(1)
#define SP0   __builtin_amdgcn_s_setprio(0)

__global__ __launch_bounds__(512, 2) void lstm_gemm_fused(
    const unsigned short* __restrict__ A, const unsigned short* __restrict__ W,
    const float* __restrict__ bias, const float* __restrict__ c0,
    float* __restrict__ ht, float* __restrict__ ct)
{
    __shared__ char sm[131072];

    const int tid = threadIdx.x;
    const int l   = tid & 63;
    const int w   = tid >> 6;         // wave 0..7
    const int wm  = w >> 2;           // 0..1  (row half: 128 rows)
    const int wn  = w & 3;            // 0..3  (col quarter: 64 cols)

    // XCD-aware bijective swizzle (1024 blocks, %8==0)
    const int bid = blockIdx.x;
    const int nid = (bid & 7) * 128 + (bid >> 3);
    const int bm  = nid >> 4;         // 0..63 (M tiles)
    const int bn  = nid & 15;         // 0..15 (N tiles)

    f32x16 acc[4][2];
#pragma unroll
    for (int i = 0; i < 4; ++i)
#pragma unroll
        for (int j = 0; j < 2; ++j)
#pragma unroll
            for (int e = 0; e < 16; ++e) acc[i][j][e] = 0.f;

    // ---- staging source addressing (inverse-swizzled, incl. row&16 term) ----
    const int srow = w * 16 + (l >> 2);                 // 0..127
    const int scb  = (((l & 3) << 4) ^ (l & 32)) ^ ((w & 1) << 4);
    const char* Asrc = (const char*)A + (size_t)(bm * 256 + srow) * KB + scb;
    const char* Wsrc = (const char*)W + (size_t)(bn * 256 + srow) * KB + scb;
    const uint32_t wL = (uint32_t)w * 1024u;            // wave-uniform LDS dest part

    // stage one kk-half of A AND B for the tile at the current pointers (4 gloads)
#define STAGE_AB(KK, BOFF) do { \
    gload16(Asrc + (KK) * 64,            sm + (BOFF) + (KK) * 16384u + wL); \
    gload16(Asrc + (KK) * 64 + 128 * KB, sm + (BOFF) + (KK) * 16384u + 8192u + wL); \
    gload16(Wsrc + (KK) * 64,            sm + (BOFF) + 32768u + (KK) * 16384u + wL); \
    gload16(Wsrc + (KK) * 64 + 128 * KB, sm + (BOFF) + 32768u + (KK) * 16384u + 8192u + wL); \
} while (0)
#define BUMP do { Asrc += 128; Wsrc += 128; } while (0)

    // ---- 32x32x16 fragment read addressing (conflict-fixed swizzle) ----
    const uint32_t sp    = (uint32_t)((l >> 4) & 1);
    const uint32_t col0  = (((uint32_t)(l >> 5)) * 16u)
                         ^ ((uint32_t)(l & 8) << 2) ^ (sp << 4);
    const uint32_t lane0 = sp * 1024u + (uint32_t)(l & 15) * 64u + col0;  // ks=0
    const uint32_t lane1 = lane0 ^ 32u;                                   // ks=1
    const uint32_t ArdB  = (uint32_t)wm * 8192u;            // + chunk + mf*2048 + laneK
    const uint32_t BrdB  = 32768u + (uint32_t)wn * 4096u;   // + chunk + nf*2048 + laneK

    bf16x8 aX[4][2], aY[4][2], bb[2][2];

#define RD_A8(BOFF, KK, ARR) do { \
    const uint32_t cb_ = (BOFF) + (KK) * 16384u; \
    _Pragma("unroll") \
    for (int mf_ = 0; mf_ < 4; ++mf_) { \
        ARR[mf_][0] = *(const bf16x8*)(sm + cb_ + ArdB + mf_ * 2048u + lane0); \
        ARR[mf_][1] = *(const bf16x8*)(sm + cb_ + ArdB + mf_ * 2048u + lane1); \
    } \
} while (0)
#define RD_B4(BOFF, KK) do { \
    const uint32_t cb_ = (BOFF) + (KK) * 16384u; \
    _Pragma("unroll") \
    for (int nf_ = 0; nf_ < 2; ++nf_) { \
        bb[nf_][0] = *(const bf16x8*)(sm + cb_ + BrdB + nf_ * 2048u + lane0); \
        bb[nf_][1] = *(const bf16x8*)(sm + cb_ + BrdB + nf_ * 2048u + lane1); \
    } \
} while (0)

#define MFMA16(ARR) do { \
    SP1; \
    _Pragma("unroll") \
    for (int ks_ = 0; ks_ < 2; ++ks_) \
        _Pragma("unroll") \
        for (int mf_ = 0; mf_ < 4; ++mf_) \
            _Pragma("unroll") \
            for (int nf_ = 0; nf_ < 2; ++nf_) \
                acc[mf_][nf_] = __builtin_amdgcn_mfma_f32_32x32x16_bf16( \
                    ARR[mf_][ks_], bb[nf_][ks_], acc[mf_][nf_], 0, 0, 0); \
    SP0; \
} while (0)

    // ---- prologue: stage tile0 (8 loads), then windows w0, w1 ----
    STAGE_AB(0, BUF0); STAGE_AB(1, BUF0);
    BUMP;                              // ptr -> t1
    // w0 (T=0,kk0): no B-read, no MFMA
    VM4; BAR; FENCE;
    RD_A8(BUF0, 0, aX);
    STAGE_AB(0, BUF1);                 // t1 kk0
    // w1 (T=0,kk1): MFMA (t0,kk0)
    VM4; BAR; FENCE;
    RD_B4(BUF0, 0);
    RD_A8(BUF0, 1, aY);
    STAGE_AB(1, BUF1);                 // t1 kk1
    BUMP;                              // ptr -> t2
    MFMA16(aX);

    // ---- main loop: tiles T=1..31 (2 windows each); AB = T's buffer, NB = next ----
#define DO_TILE(AB, NB) do { \
    /* wA (kk0): MFMA (T-1,kk1); prev tile's buffer == NB */ \
    VM4; BAR; FENCE; \
    RD_B4(NB, 1); \
    RD_A8(AB, 0, aX); \
    STAGE_AB(0, NB); \
    MFMA16(aY); \
    /* wB (kk1): MFMA (T,kk0) */ \
    VM4; BAR; FENCE; \
    RD_B4(AB, 0); \
    RD_A8(AB, 1, aY); \
    STAGE_AB(1, NB); \
    BUMP; \
    MFMA16(aX); \
} while (0)

#pragma unroll 1
    for (int tt = 1; tt < NT - 1; tt += 2) {
        DO_TILE(BUF1, BUF0);           // odd tile
        DO_TILE(BUF0, BUF1);           // even tile
    }
    DO_TILE(BUF1, BUF0);               // T=31 (stages harmless t32 garbage)

    // tail: MFMA (t31,kk1); region staged at T=30 wB, long landed; no new stage
    FENCE;
    RD_B4(BUF1, 1);
    MFMA16(aY);

    // ---- fused LSTM epilogue (32x32 C/D map, r7-verified) ----
    asm volatile("s_waitcnt vmcnt(0) lgkmcnt(0)" ::: "memory");
    FENCE; BAR;

    float* ep = (float*)(void*)sm + w * 2176;   // 32 rows x 68 floats per wave
    const int hbase = bn * 64 + wn * 16;
    const int rbase = bm * 256 + wm * 128;
    const int rl = (l >> 5) * 4;
    const int cl = l & 31;

#pragma unroll
    for (int mf = 0; mf < 4; ++mf) {
        // scatter acc[mf][*] (32 rows x 64 cols) to LDS, padded stride 68
#pragma unroll
        for (int nf = 0; nf < 2; ++nf)
#pragma unroll
            for (int g = 0; g < 4; ++g)
#pragma unroll
                for (int ri = 0; ri < 4; ++ri)
                    ep[(ri + g * 8 + rl) * 68 + nf * 32 + cl] = acc[mf][nf][g * 4 + ri];

        // gather: 512 cells = 32 rows x 16 h-quads; lane handles 8
#pragma unroll
        for (int it = 0; it < 8; ++it) {
            const int c   = it * 64 + l;
            const int row = c >> 4;
            const int hq  = c & 15;
            f32x4 z = *(const f32x4*)(ep + row * 68 + hq * 4);
            const int hg = hbase + hq;
            const float4 bz = ((const float4*)bias)[hg];
            const int brow = rbase + mf * 32 + row;

            float zf = z.x + bz.x;
            float zi = z.y + bz.y;
            float zo = z.z + bz.z;
            float zg = z.w + bz.w;

            float fg = rcp1p(__expf(-zf));                   // sigmoid
            float ig = rcp1p(__expf(-zi));
            float og = rcp1p(__expf(-zo));
            float gg = 2.f * rcp1p(__expf(-2.f * zg)) - 1.f; // tanh

            int64_t oi = (int64_t)brow * H_DIM + hg;
            float cc = fg * c0[oi] + ig * gg;
            float hh = og * (2.f * rcp1p(__expf(-2.f * cc)) - 1.f);
            ct[oi] = cc;
            ht[oi] = hh;
        }
    }
}

extern "C" void kernel_launch(void* const* d_in, const int* in_sizes, int n_in,
                              void* d_out, int out_size, void* d_ws, size_t ws_size,
                              hipStream_t stream) {
    const float* x  = (const float*)d_in[0];
    const float* h0 = (const float*)d_in[1];
    const float* c0 = (const float*)d_in[2];
    const float* wi = (const float*)d_in[3];
    const float* bi = (const float*)d_in[4];
    const float* wh = (const float*)d_in[5];
    const float* bh = (const float*)d_in[6];

    float* ht = (float*)d_out;
    float* ct = ht + (int64_t)B_ROWS * H_DIM;

    char* ws = (char*)d_ws;
    unsigned short* A  = (unsigned short*)ws;                       // 64 MiB
    unsigned short* Wp = (unsigned short*)(ws + (64u << 20));       // 16 MiB
    float*          bs = (float*)(ws + (80u << 20));                // 16 KiB

    pack_a_kernel<<<32768, 256, 0, stream>>>(x, h0, A);
    pack_w_kernel<<<8192, 256, 0, stream>>>(wi, wh, bi, bh, Wp, bs);

    lstm_gemm_fused<<<1024, 512, 0, stream>>>(A, Wp, bs, c0, ht, ct);
}

// Round 9
// 306.453 us; speedup vs baseline: 1.1227x; 1.0904x over previous
//
#include <hip/hip_runtime.h>
#include <hip/hip_bf16.h>
#include <stdint.h>

#define B_ROWS 16384
#define K_DIM  2048   // IN + H
#define H_DIM  1024
#define N_DIM  4096   // 4*H
#define KB     (K_DIM * 2)      // bytes per packed row (4096)
#define NT     (K_DIM / 64)     // 32 K-tiles of BK=64
#define BUF0   0u
#define BUF1   65536u           // LDS double buffer: A 32K + B 32K each

using f32x4  = __attribute__((ext_vector_type(4))) float;
using bf16x8 = __attribute__((ext_vector_type(8))) __bf16;

// RNE float -> bf16 (inputs are finite)
__device__ __forceinline__ unsigned short f2bf(float f) {
    union { float f; unsigned u; } v; v.f = f;
    unsigned r = v.u + 0x7fffu + ((v.u >> 16) & 1u);
    return (unsigned short)(r >> 16);
}

// async global->LDS, 16B/lane. LDS dest must be wave-uniform (HW adds lane*16).
__device__ __forceinline__ void gload16(const void* g, const void* l) {
    __builtin_amdgcn_global_load_lds(
        (const __attribute__((address_space(1))) void*)g,
        (__attribute__((address_space(3))) void*)l,
        16, 0, 0);
}

__device__ __forceinline__ float rcp1p(float e) {   // 1/(1+e)
    return __builtin_amdgcn_rcpf(1.f + e);
}

// ---------------- pack kernels (unchanged, verified) ----------------
__global__ void pack_a_kernel(const float* __restrict__ x, const float* __restrict__ h0,
                              unsigned short* __restrict__ A) {
    int tid = blockIdx.x * 256 + threadIdx.x;
    int64_t idx = (int64_t)tid * 4;
    int b = (int)(idx >> 11);
    int k = (int)(idx & 2047);
    const float* src = (k < 1024) ? (x + (int64_t)b * 1024 + k)
                                  : (h0 + (int64_t)b * 1024 + (k - 1024));
    float4 v = *(const float4*)src;
    ushort4 o;
    o.x = f2bf(v.x); o.y = f2bf(v.y); o.z = f2bf(v.z); o.w = f2bf(v.w);
    *(ushort4*)(A + idx) = o;
}

__global__ void pack_w_kernel(const float* __restrict__ wi, const float* __restrict__ wh,
                              const float* __restrict__ bi, const float* __restrict__ bh,
                              unsigned short* __restrict__ W, float* __restrict__ bias) {
    int tid = blockIdx.x * 256 + threadIdx.x;
    int64_t idx = (int64_t)tid * 4;
    int r = (int)(idx >> 11);
    int k = (int)(idx & 2047);
    int h = r >> 2, g = r & 3;
    const float* src = (k < 1024)
        ? (wi + (int64_t)g * 1048576 + (int64_t)h * 1024 + k)
        : (wh + (int64_t)g * 1048576 + (int64_t)h * 1024 + (k - 1024));
    float4 v = *(const float4*)src;
    ushort4 o;
    o.x = f2bf(v.x); o.y = f2bf(v.y); o.z = f2bf(v.z); o.w = f2bf(v.w);
    *(ushort4*)(W + idx) = o;
    if (k == 0) bias[r] = bi[g * 1024 + h] + bh[g * 1024 + h];
}

// -------- 256x256 counted-lgkm read-ahead GEMM + fused LSTM epilogue --------
// LDS buffer (x2 @ 0/65536): A kk0 @0 (16K), A kk1 @16384, B kk0 @32768, B kk1 @49152.
// Layout/swizzle/staging/read addressing: IDENTICAL to verified r5/r6 (16x16x32).
// Phase p issues NEXT phase's ds_reads, then 2 gloads, then [vmcnt(2) if even],
// ONE barrier, lgkmcnt(=reads just issued) -- drains only OLDER reads (this
// phase's MFMA operands) -- then 16 MFMA while the new reads drain underneath.
//
// Hazard ledger (phases 4t+0..3; stage slots: ph0:A-kk0(t+1) ph1:B-kk0 ph2:A-kk1 ph3:B-kk1):
//  RAW  kk1(t)   read @ph1: staged ph2,ph3(t-1); vmcnt(2)@ph0 (outstanding 6:
//        those 4 + ph0's 2) drains them BEFORE BAR(ph0). reads after BAR(ph0). OK
//  RAW  kk0(t+1) read @ph3: staged ph0,ph1(t); vmcnt(2)@ph2 drains them before
//        BAR(ph2); reads after BAR(ph2). OK
//  WAR-LDS  stage->NXT @ph0(t): NXT last ds-read @ph2(t-1) (aH1); those retire
//        at LGKM8@ph3(t-1) before BAR(ph3,t-1); stage issued after that BAR. OK
//  WAR-regs 6 operand banks; every bank's write trails its last MFMA reader by
//        >=2 phases (aL0: used ph0, rewritten ph3; bb0: used ph1, rewritten ph3;
//        aH0: used ph1, rewritten ph0(t+1); etc.). OK
//  LGKM exactness: per-wave DS FIFO, loop has no other lgkm ops (global_* are
//        vmcnt-only). ph0/ph2 issue 4 reads -> LGKM4; ph1/ph3 issue 8 -> LGKM8.

#define FENCE   asm volatile("" ::: "memory")
#define BARRIER do { FENCE; __builtin_amdgcn_s_barrier(); FENCE; } while (0)
#define VM2     asm volatile("s_waitcnt vmcnt(2)" ::: "memory")
#define LGKM4   asm volatile("s_waitcnt lgkmcnt(4)" ::: "memory")
#define LGKM8   asm volatile("s_waitcnt lgkmcnt(8)" ::: "memory")
#define SP1     __builtin_amdgcn_s_setprio(1)
#define SP0     __builtin_amdgcn_s_setprio(0)

__global__ __launch_bounds__(512, 2) void lstm_gemm_fused(
    const unsigned short* __restrict__ A, const unsigned short* __restrict__ W,
    const float* __restrict__ bias, const float* __restrict__ c0,
    float* __restrict__ ht, float* __restrict__ ct)
{
    __shared__ char sm[131072];

    const int tid = threadIdx.x;
    const int l   = tid & 63;
    const int w   = tid >> 6;         // wave 0..7
    const int wm  = w >> 2;           // 0..1  (row half: 128 rows)
    const int wn  = w & 3;            // 0..3  (col quarter: 64 cols)

    // XCD-aware bijective swizzle (1024 blocks, %8==0)
    const int bid = blockIdx.x;
    const int nid = (bid & 7) * 128 + (bid >> 3);
    const int bm  = nid >> 4;         // 0..63 (M tiles)
    const int bn  = nid & 15;         // 0..15 (N tiles)

    f32x4 acc[8][4];
#pragma unroll
    for (int i = 0; i < 8; ++i)
#pragma unroll
        for (int j = 0; j < 4; ++j) acc[i][j] = (f32x4){0.f, 0.f, 0.f, 0.f};

    // ---- staging source addressing (inverse-swizzled), pointer-bumped per tile ----
    const int srow = w * 16 + (l >> 2);                 // 0..127
    const int scb  = ((l & 3) << 4) ^ (l & 32);
    const char* Asrc = (const char*)A + (size_t)(bm * 256 + srow) * KB + scb;
    const char* Wsrc = (const char*)W + (size_t)(bn * 256 + srow) * KB + scb;
    const uint32_t wL = (uint32_t)w * 1024u;            // wave-uniform LDS dest part

#define STAGE_A(KK, BOFF) do { \
    gload16(Asrc + (KK) * 64,            sm + (BOFF) + (KK) * 16384u + wL); \
    gload16(Asrc + (KK) * 64 + 128 * KB, sm + (BOFF) + (KK) * 16384u + 8192u + wL); \
} while (0)
#define STAGE_B(KK, BOFF) do { \
    gload16(Wsrc + (KK) * 64,            sm + (BOFF) + 32768u + (KK) * 16384u + wL); \
    gload16(Wsrc + (KK) * 64 + 128 * KB, sm + (BOFF) + 32768u + (KK) * 16384u + 8192u + wL); \
} while (0)
#define BUMP do { Asrc += 128; Wsrc += 128; } while (0)

    // ---- fragment read addressing (swizzled, r5-verified) ----
    const int rr = l & 15, kg = l >> 4;
    const uint32_t loff = (uint32_t)rr * 64u + (((uint32_t)kg * 16u) ^ (uint32_t)((rr & 8) << 2));
    const uint32_t Ard = (uint32_t)wm * 8192u + loff;             // + BOFF + KK*16384 + mf*1024
    const uint32_t Brd = 32768u + (uint32_t)wn * 4096u + loff;    // + BOFF + KK*16384 + nf*1024

    bf16x8 aL0[4], aH0[4], aL1[4], aH1[4], bb0[4], bb1[4];

#define RD_A4(BOFF, KK, MB, ARR) do { \
    _Pragma("unroll") \
    for (int i_ = 0; i_ < 4; ++i_) \
        ARR[i_] = *(const bf16x8*)(sm + (BOFF) + (KK) * 16384u + Ard + ((MB) + i_) * 1024u); \
} while (0)
#define RD_B4(BOFF, KK, BRR) do { \
    _Pragma("unroll") \
    for (int i_ = 0; i_ < 4; ++i_) \
        BRR[i_] = *(const bf16x8*)(sm + (BOFF) + (KK) * 16384u + Brd + i_ * 1024u); \
} while (0)

#define MFMA16H(ARR, MB, BRR) do { \
    _Pragma("unroll") \
    for (int mf_ = 0; mf_ < 4; ++mf_) \
        _Pragma("unroll") \
        for (int nf_ = 0; nf_ < 4; ++nf_) \
            acc[(MB) + mf_][nf_] = __builtin_amdgcn_mfma_f32_16x16x32_bf16( \
                ARR[mf_], BRR[nf_], acc[(MB) + mf_][nf_], 0, 0, 0); \
} while (0)

    // ---- prologue: stage tile0; drain kk0 (kk1's 4 stay in flight = steady state);
    //      issue "phase -1" reads (ph0 operands) ----
    STAGE_A(0, BUF0); STAGE_B(0, BUF0);   // kk0 t0 (4)
    STAGE_A(1, BUF0); STAGE_B(1, BUF0);   // kk1 t0 (4)
    BUMP;                                 // ptr -> t1
    asm volatile("s_waitcnt vmcnt(4)" ::: "memory");
    BARRIER;
    RD_A4(BUF0, 0, 0, aL0); RD_B4(BUF0, 0, bb0);   // 8 reads outstanding

    // ---- main loop: 4 single-barrier phases per tile ----
#define DO_TILE(CUR, NXT) do { \
    /* ph0: rd aH(kk0); stage A-kk0(t+1); MFMA (kk0, mf0-3) */ \
    RD_A4(CUR, 0, 4, aH0); \
    STAGE_A(0, NXT); \
    VM2; BARRIER; LGKM4; SP1; MFMA16H(aL0, 0, bb0); SP0; \
    /* ph1: rd aL+bb(kk1); stage B-kk0(t+1); MFMA (kk0, mf4-7) */ \
    RD_A4(CUR, 1, 0, aL1); RD_B4(CUR, 1, bb1); \
    STAGE_B(0, NXT); \
    BARRIER; LGKM8; SP1; MFMA16H(aH0, 4, bb0); SP0; \
    /* ph2: rd aH(kk1); stage A-kk1(t+1); MFMA (kk1, mf0-3) */ \
    RD_A4(CUR, 1, 4, aH1); \
    STAGE_A(1, NXT); \
    VM2; BARRIER; LGKM4; SP1; MFMA16H(aL1, 0, bb1); SP0; \
    /* ph3: rd aL+bb(kk0, t+1) from NXT; stage B-kk1(t+1); MFMA (kk1, mf4-7) */ \
    RD_A4(NXT, 0, 0, aL0); RD_B4(NXT, 0, bb0); \
    STAGE_B(1, NXT); \
    BUMP; \
    BARRIER; LGKM8; SP1; MFMA16H(aH1, 4, bb1); SP0; \
} while (0)

#pragma unroll 1
    for (int tt = 0; tt < NT; tt += 2) {
        DO_TILE(BUF0, BUF1);
        DO_TILE(BUF1, BUF0);
    }
    // (final tile's ph3 reads t32 garbage into aL0/bb0 -- never consumed;
    //  its stages land in BUF1 -- never read. Sources stay inside d_ws.)

    // ---- fused LSTM epilogue (r5-verified) ----
    asm volatile("s_waitcnt vmcnt(0) lgkmcnt(0)" ::: "memory");
    BARRIER;

    float* ep = (float*)(void*)sm + w * 1088;   // 16 rows x 68 floats per wave
    const int hbase = bn * 64 + wn * 16;
    const int rbase = bm * 256 + wm * 128;

#pragma unroll
    for (int mf = 0; mf < 8; ++mf) {
        // scatter acc slice (16 rows x 64 cols) to LDS, padded stride 68
#pragma unroll
        for (int nf = 0; nf < 4; ++nf)
#pragma unroll
            for (int r = 0; r < 4; ++r)
                ep[((l >> 4) * 4 + r) * 68 + nf * 16 + (l & 15)] = acc[mf][nf][r];

        // gather: lane -> (row, h); cols 4h..4h+3 = gates f,i,o,g
#pragma unroll
        for (int it = 0; it < 4; ++it) {
            const int row = (l >> 4) + it * 4;
            const int hs  = l & 15;
            f32x4 z = *(const f32x4*)(ep + row * 68 + hs * 4);
            const int hg = hbase + hs;
            const float4 bz = ((const float4*)bias)[hg];
            const int brow = rbase + mf * 16 + row;

            float zf = z.x + bz.x;
            float zi = z.y + bz.y;
            float zo = z.z + bz.z;
            float zg = z.w + bz.w;

            float fg = rcp1p(__expf(-zf));                   // sigmoid
            float ig = rcp1p(__expf(-zi));
            float og = rcp1p(__expf(-zo));
            float gg = 2.f * rcp1p(__expf(-2.f * zg)) - 1.f; // tanh

            int64_t oi = (int64_t)brow * H_DIM + hg;
            float c  = fg * c0[oi] + ig * gg;
            float hh = og * (2.f * rcp1p(__expf(-2.f * c)) - 1.f);
            ct[oi] = c;
            ht[oi] = hh;
        }
    }
}

extern "C" void kernel_launch(void* const* d_in, const int* in_sizes, int n_in,
                              void* d_out, int out_size, void* d_ws, size_t ws_size,
                              hipStream_t stream) {
    const float* x  = (const float*)d_in[0];
    const float* h0 = (const float*)d_in[1];
    const float* c0 = (const float*)d_in[2];
    const float* wi = (const float*)d_in[3];
    const float* bi = (const float*)d_in[4];
    const float* wh = (const float*)d_in[5];
    const float* bh = (const float*)d_in[6];

    float* ht = (float*)d_out;
    float* ct = ht + (int64_t)B_ROWS * H_DIM;

    char* ws = (char*)d_ws;
    unsigned short* A  = (unsigned short*)ws;                       // 64 MiB
    unsigned short* Wp = (unsigned short*)(ws + (64u << 20));       // 16 MiB
    float*          bs = (float*)(ws + (80u << 20));                // 16 KiB

    pack_a_kernel<<<32768, 256, 0, stream>>>(x, h0, A);
    pack_w_kernel<<<8192, 256, 0, stream>>>(wi, wh, bi, bh, Wp, bs);

    lstm_gemm_fused<<<1024, 512, 0, stream>>>(A, Wp, bs, c0, ht, ct);
}

// Round 10
// 303.931 us; speedup vs baseline: 1.1320x; 1.0083x over previous
//
#include <hip/hip_runtime.h>
#include <hip/hip_bf16.h>
#include <stdint.h>

#define B_ROWS 16384
#define K_DIM  2048   // IN + H
#define H_DIM  1024
#define N_DIM  4096   // 4*H
#define KB     (K_DIM * 2)      // bytes per packed row (4096)
#define NT     (K_DIM / 64)     // 32 K-tiles of BK=64
#define BUF0   0u
#define BUF1   65536u           // LDS double buffer: A 32K + B 32K each

using f32x4  = __attribute__((ext_vector_type(4))) float;
using bf16x8 = __attribute__((ext_vector_type(8))) __bf16;

// RNE float -> bf16 (inputs are finite)
__device__ __forceinline__ unsigned short f2bf(float f) {
    union { float f; unsigned u; } v; v.f = f;
    unsigned r = v.u + 0x7fffu + ((v.u >> 16) & 1u);
    return (unsigned short)(r >> 16);
}

// async global->LDS, 16B/lane. LDS dest must be wave-uniform (HW adds lane*16).
__device__ __forceinline__ void gload16(const void* g, const void* l) {
    __builtin_amdgcn_global_load_lds(
        (const __attribute__((address_space(1))) void*)g,
        (__attribute__((address_space(3))) void*)l,
        16, 0, 0);
}

__device__ __forceinline__ float rcp1p(float e) {   // 1/(1+e)
    return __builtin_amdgcn_rcpf(1.f + e);
}

// ---------------- pack kernels (unchanged, verified) ----------------
__global__ void pack_a_kernel(const float* __restrict__ x, const float* __restrict__ h0,
                              unsigned short* __restrict__ A) {
    int tid = blockIdx.x * 256 + threadIdx.x;
    int64_t idx = (int64_t)tid * 4;
    int b = (int)(idx >> 11);
    int k = (int)(idx & 2047);
    const float* src = (k < 1024) ? (x + (int64_t)b * 1024 + k)
                                  : (h0 + (int64_t)b * 1024 + (k - 1024));
    float4 v = *(const float4*)src;
    ushort4 o;
    o.x = f2bf(v.x); o.y = f2bf(v.y); o.z = f2bf(v.z); o.w = f2bf(v.w);
    *(ushort4*)(A + idx) = o;
}

__global__ void pack_w_kernel(const float* __restrict__ wi, const float* __restrict__ wh,
                              const float* __restrict__ bi, const float* __restrict__ bh,
                              unsigned short* __restrict__ W, float* __restrict__ bias) {
    int tid = blockIdx.x * 256 + threadIdx.x;
    int64_t idx = (int64_t)tid * 4;
    int r = (int)(idx >> 11);
    int k = (int)(idx & 2047);
    int h = r >> 2, g = r & 3;
    const float* src = (k < 1024)
        ? (wi + (int64_t)g * 1048576 + (int64_t)h * 1024 + k)
        : (wh + (int64_t)g * 1048576 + (int64_t)h * 1024 + (k - 1024));
    float4 v = *(const float4*)src;
    ushort4 o;
    o.x = f2bf(v.x); o.y = f2bf(v.y); o.z = f2bf(v.z); o.w = f2bf(v.w);
    *(ushort4*)(W + idx) = o;
    if (k == 0) bias[r] = bi[g * 1024 + h] + bh[g * 1024 + h];
}

// ------ 256x256 GEMM: SGB-interleaved {MFMA || next-bank ds_read || stage} ------
// LDS buffer (x2 @ 0/65536): A kk0 @0 (16K), A kk1 @16384, B kk0 @32768, B kk1 @49152.
// Layout/swizzle/staging/read addressing: IDENTICAL to verified r5/r6/r9 (16x16x32).
// Per K-tile 4 regions, each: BAR; lgkm0 (free: operands drained under prev region);
// sched_barrier(0); setprio1; SGB-forced interleave of {16 MFMA (prev bank), 4-8
// ds_reads (next bank), 2 gloads}; setprio0; [VM2 at A/C]; BAR.
//
// Hazard ledger (regions A,B,C,D per tile; stage slots A:Akk0 B:Bkk0 C:Akk1 D:Bkk1,
// all -> NXT; VM2 = wait vmcnt<=2 at end of A and C):
//  RAW D(t) reads NXT.kk0 (aL0',bb0'): staged A(t),B(t); VM2@C(t) (6->2) drains
//      them before BAR(C) < D's reads. OK
//  RAW B(t) reads CUR.kk1 (aL1,bb1): staged C(t-1),D(t-1); VM2@A(t) drains them
//      before BAR(A) < B's reads. OK
//  RAW A(t) reads aH0 (CUR.kk0): staged A,B(t-1), drained @VM2-C(t-1). OK
//  RAW C(t) reads aH1 (CUR.kk1): staged C,D(t-1), drained @VM2-A(t). OK
//  WAR-LDS: every stage into region X follows >=2 barriers after the last ds_read
//      of X, with an interposed all-wave lgkm0 (region tops) forcing read retire.
//  WAR-regs: 6 banks; every bank write trails its last MFMA reader by >=1 region
//      boundary (aL0:rd A wr D; aH0:rd B wr A'; aL1:rd C wr B'; aH1:rd D wr C';
//      bb0:rd A,B wr D; bb1:rd C,D wr B'). Within-region MFMA(prev bank) never
//      aliases the writes (cur bank). OK -> interleave is hazard-free.

#define FENCE   asm volatile("" ::: "memory")
#define BARRIER do { FENCE; __builtin_amdgcn_s_barrier(); FENCE; } while (0)
#define VM2     asm volatile("s_waitcnt vmcnt(2)" ::: "memory")
#define LGKM0   asm volatile("s_waitcnt lgkmcnt(0)" ::: "memory")
#define SCHED0  __builtin_amdgcn_sched_barrier(0)
#define SP1     __builtin_amdgcn_s_setprio(1)
#define SP0     __builtin_amdgcn_s_setprio(0)
#define SGB(MASK, N) __builtin_amdgcn_sched_group_barrier((MASK), (N), 0)

// interleave patterns: reads early (drain under trailing MFMAs); masks per LLVM:
// MFMA=0x8, VMEM_READ=0x20, DS_READ=0x100
#define SGB_PAT4 do { \
    _Pragma("unroll") for (int s_ = 0; s_ < 4; ++s_) { SGB(0x8,1); SGB(0x100,1); } \
    _Pragma("unroll") for (int s_ = 0; s_ < 2; ++s_) { SGB(0x8,1); SGB(0x20,1); } \
    SGB(0x8,10); } while (0)
#define SGB_PAT8 do { \
    _Pragma("unroll") for (int s_ = 0; s_ < 8; ++s_) { SGB(0x8,1); SGB(0x100,1); } \
    _Pragma("unroll") for (int s_ = 0; s_ < 2; ++s_) { SGB(0x8,1); SGB(0x20,1); } \
    SGB(0x8,6); } while (0)

__global__ __launch_bounds__(512, 2) void lstm_gemm_fused(
    const unsigned short* __restrict__ A, const unsigned short* __restrict__ W,
    const float* __restrict__ bias, const float* __restrict__ c0,
    float* __restrict__ ht, float* __restrict__ ct)
{
    __shared__ char sm[131072];

    const int tid = threadIdx.x;
    const int l   = tid & 63;
    const int w   = tid >> 6;         // wave 0..7
    const int wm  = w >> 2;           // 0..1  (row half: 128 rows)
    const int wn  = w & 3;            // 0..3  (col quarter: 64 cols)

    // XCD-aware bijective swizzle (1024 blocks, %8==0)
    const int bid = blockIdx.x;
    const int nid = (bid & 7) * 128 + (bid >> 3);
    const int bm  = nid >> 4;         // 0..63 (M tiles)
    const int bn  = nid & 15;         // 0..15 (N tiles)

    f32x4 acc[8][4];
#pragma unroll
    for (int i = 0; i < 8; ++i)
#pragma unroll
        for (int j = 0; j < 4; ++j) acc[i][j] = (f32x4){0.f, 0.f, 0.f, 0.f};

    // ---- staging source addressing (inverse-swizzled), pointer-bumped per tile ----
    const int srow = w * 16 + (l >> 2);                 // 0..127
    const int scb  = ((l & 3) << 4) ^ (l & 32);
    const char* Asrc = (const char*)A + (size_t)(bm * 256 + srow) * KB + scb;
    const char* Wsrc = (const char*)W + (size_t)(bn * 256 + srow) * KB + scb;
    const uint32_t wL = (uint32_t)w * 1024u;            // wave-uniform LDS dest part

#define STAGE_A(KK, BOFF) do { \
    gload16(Asrc + (KK) * 64,            sm + (BOFF) + (KK) * 16384u + wL); \
    gload16(Asrc + (KK) * 64 + 128 * KB, sm + (BOFF) + (KK) * 16384u + 8192u + wL); \
} while (0)
#define STAGE_B(KK, BOFF) do { \
    gload16(Wsrc + (KK) * 64,            sm + (BOFF) + 32768u + (KK) * 16384u + wL); \
    gload16(Wsrc + (KK) * 64 + 128 * KB, sm + (BOFF) + 32768u + (KK) * 16384u + 8192u + wL); \
} while (0)
#define BUMP do { Asrc += 128; Wsrc += 128; } while (0)

    // ---- fragment read addressing (swizzled, r5-verified) ----
    const int rr = l & 15, kg = l >> 4;
    const uint32_t loff = (uint32_t)rr * 64u + (((uint32_t)kg * 16u) ^ (uint32_t)((rr & 8) << 2));
    const uint32_t Ard = (uint32_t)wm * 8192u + loff;             // + BOFF + KK*16384 + mf*1024
    const uint32_t Brd = 32768u + (uint32_t)wn * 4096u + loff;    // + BOFF + KK*16384 + nf*1024

    bf16x8 aL0[4], aH0[4], aL1[4], aH1[4], bb0[4], bb1[4];

#define RD_A4(BOFF, KK, MB, ARR) do { \
    _Pragma("unroll") \
    for (int i_ = 0; i_ < 4; ++i_) \
        ARR[i_] = *(const bf16x8*)(sm + (BOFF) + (KK) * 16384u + Ard + ((MB) + i_) * 1024u); \
} while (0)
#define RD_B4(BOFF, KK, BRR) do { \
    _Pragma("unroll") \
    for (int i_ = 0; i_ < 4; ++i_) \
        BRR[i_] = *(const bf16x8*)(sm + (BOFF) + (KK) * 16384u + Brd + i_ * 1024u); \
} while (0)

#define MFMA16H(ARR, MB, BRR) do { \
    _Pragma("unroll") \
    for (int mf_ = 0; mf_ < 4; ++mf_) \
        _Pragma("unroll") \
        for (int nf_ = 0; nf_ < 4; ++nf_) \
            acc[(MB) + mf_][nf_] = __builtin_amdgcn_mfma_f32_16x16x32_bf16( \
                ARR[mf_], BRR[nf_], acc[(MB) + mf_][nf_], 0, 0, 0); \
} while (0)

    // ---- prologue: stage tile0 (slots Akk0,Bkk0,Akk1,Bkk1); drain kk0;
    //      pre-read region-A's operands (aL0, bb0 of t0 kk0) ----
    STAGE_A(0, BUF0); STAGE_B(0, BUF0);
    STAGE_A(1, BUF0); STAGE_B(1, BUF0);
    BUMP;                                 // ptr -> t1
    asm volatile("s_waitcnt vmcnt(4)" ::: "memory");
    BARRIER;
    RD_A4(BUF0, 0, 0, aL0); RD_B4(BUF0, 0, bb0);

    // ---- main loop: 4 merged regions per tile ----
#define DO_TILE(CUR, NXT) do { \
    /* region A: MFMA(kk0 lo) || rd aH0 || stage A-kk0 */ \
    LGKM0; SCHED0; SP1; \
    RD_A4(CUR, 0, 4, aH0); \
    STAGE_A(0, NXT); \
    MFMA16H(aL0, 0, bb0); \
    SGB_PAT4; \
    SP0; VM2; BARRIER; \
    /* region B: MFMA(kk0 hi) || rd aL1+bb1 || stage B-kk0 */ \
    LGKM0; SCHED0; SP1; \
    RD_A4(CUR, 1, 0, aL1); RD_B4(CUR, 1, bb1); \
    STAGE_B(0, NXT); \
    MFMA16H(aH0, 4, bb0); \
    SGB_PAT8; \
    SP0; BARRIER; \
    /* region C: MFMA(kk1 lo) || rd aH1 || stage A-kk1 */ \
    LGKM0; SCHED0; SP1; \
    RD_A4(CUR, 1, 4, aH1); \
    STAGE_A(1, NXT); \
    MFMA16H(aL1, 0, bb1); \
    SGB_PAT4; \
    SP0; VM2; BARRIER; \
    /* region D: MFMA(kk1 hi) || rd aL0'+bb0' (NXT kk0) || stage B-kk1 */ \
    LGKM0; SCHED0; SP1; \
    RD_A4(NXT, 0, 0, aL0); RD_B4(NXT, 0, bb0); \
    STAGE_B(1, NXT); \
    MFMA16H(aH1, 4, bb1); \
    SGB_PAT8; \
    SP0; BARRIER; \
    BUMP; \
} while (0)

#pragma unroll 1
    for (int tt = 0; tt < NT; tt += 2) {
        DO_TILE(BUF0, BUF1);
        DO_TILE(BUF1, BUF0);
    }
    // (final tile's region D reads t32 garbage into aL0/bb0 -- never consumed;
    //  its stages land in BUF1 -- never read. Sources stay inside d_ws.)

    // ---- fused LSTM epilogue (r5-verified) ----
    asm volatile("s_waitcnt vmcnt(0) lgkmcnt(0)" ::: "memory");
    BARRIER;

    float* ep = (float*)(void*)sm + w * 1088;   // 16 rows x 68 floats per wave
    const int hbase = bn * 64 + wn * 16;
    const int rbase = bm * 256 + wm * 128;

#pragma unroll
    for (int mf = 0; mf < 8; ++mf) {
        // scatter acc slice (16 rows x 64 cols) to LDS, padded stride 68
#pragma unroll
        for (int nf = 0; nf < 4; ++nf)
#pragma unroll
            for (int r = 0; r < 4; ++r)
                ep[((l >> 4) * 4 + r) * 68 + nf * 16 + (l & 15)] = acc[mf][nf][r];

        // gather: lane -> (row, h); cols 4h..4h+3 = gates f,i,o,g
#pragma unroll
        for (int it = 0; it < 4; ++it) {
            const int row = (l >> 4) + it * 4;
            const int hs  = l & 15;
            f32x4 z = *(const f32x4*)(ep + row * 68 + hs * 4);
            const int hg = hbase + hs;
            const float4 bz = ((const float4*)bias)[hg];
            const int brow = rbase + mf * 16 + row;

            float zf = z.x + bz.x;
            float zi = z.y + bz.y;
            float zo = z.z + bz.z;
            float zg = z.w + bz.w;

            float fg = rcp1p(__expf(-zf));                   // sigmoid
            float ig = rcp1p(__expf(-zi));
            float og = rcp1p(__expf(-zo));
            float gg = 2.f * rcp1p(__expf(-2.f * zg)) - 1.f; // tanh

            int64_t oi = (int64_t)brow * H_DIM + hg;
            float c  = fg * c0[oi] + ig * gg;
            float hh = og * (2.f * rcp1p(__expf(-2.f * c)) - 1.f);
            ct[oi] = c;
            ht[oi] = hh;
        }
    }
}

extern "C" void kernel_launch(void* const* d_in, const int* in_sizes, int n_in,
                              void* d_out, int out_size, void* d_ws, size_t ws_size,
                              hipStream_t stream) {
    const float* x  = (const float*)d_in[0];
    const float* h0 = (const float*)d_in[1];
    const float* c0 = (const float*)d_in[2];
    const float* wi = (const float*)d_in[3];
    const float* bi = (const float*)d_in[4];
    const float* wh = (const float*)d_in[5];
    const float* bh = (const float*)d_in[6];

    float* ht = (float*)d_out;
    float* ct = ht + (int64_t)B_ROWS * H_DIM;

    char* ws = (char*)d_ws;
    unsigned short* A  = (unsigned short*)ws;                       // 64 MiB
    unsigned short* Wp = (unsigned short*)(ws + (64u << 20));       // 16 MiB
    float*          bs = (float*)(ws + (80u << 20));                // 16 KiB

    pack_a_kernel<<<32768, 256, 0, stream>>>(x, h0, A);
    pack_w_kernel<<<8192, 256, 0, stream>>>(wi, wh, bi, bh, Wp, bs);

    lstm_gemm_fused<<<1024, 512, 0, stream>>>(A, Wp, bs, c0, ht, ct);
}